// Round 11
// baseline (378.916 us; speedup 1.0000x reference)
//
#include <hip/hip_runtime.h>
#include <hip/hip_bf16.h>
#include <math.h>

// ChannelMambaBlock fused — Round 11: 2-wave blocks, recycled LDS, high occupancy
// B=4, C=192, H=128, W=128, K=4, DSTATE=8, DTRANK=12
// Block = 128 threads (2 waves) owning 16 consecutive-W pixels. grid = 4096.
// ONE activation buffer sX[16][200] recycled across phases: each GEMM does
// load_a (LDS->regs) -> barrier -> MFMA -> write outputs back into sX -> barrier.
// LDS ~11.4KB => ~13 blocks/CU (~6.5 waves/SIMD, vs R4's 4). x2 / z in 12+12
// packed VGPRs via parity-matched tiles (producer nt=12+wv+2j <-> consumer
// nt=wv+2j, identical lane maps). LN2 in D-layout: shfl_xor over the 16-lane
// frow group + 2-wave LDS combine. All lane mappings inherited from R4 (proven).

#define CC    192
#define HH    128
#define WW    128
#define NK    4
#define DST   8
#define DTR   12
#define NTH   128
#define SP    200         // sX row stride (400B rows, 16B-aligned)
#define SD    112         // sXD row stride (224B rows)

typedef __attribute__((ext_vector_type(8))) short bh8;   // 8 bf16 = 4 VGPR
typedef __attribute__((ext_vector_type(4))) float f4;

// bf16 weight segments inside d_ws (ushort elems)
#define OFF_WIN    0
#define OFF_SSMIN  73728        // 384*192
#define OFF_XPROJ  147456
#define OFF_SSMOUT 168960       // + 112*192
#define OFF_WOUT   205824
#define OFF_DTW    242688       // + 192*192  -> B_dt [k][c][32]
#define WTOT2      267264       // + 4*192*32
// f32 Dsum[192] at ushort offset WTOT2

#define MFMA(va, vb, vc) __builtin_amdgcn_mfma_f32_16x16x32_bf16(va, vb, vc, 0, 0, 0)

__device__ __forceinline__ float bf2f(unsigned short u) {
    union { unsigned int i; float f; } v; v.i = ((unsigned int)u) << 16; return v.f;
}
__device__ __forceinline__ unsigned short f2bf(float f) {
    __hip_bfloat16 h = __float2bfloat16(f);
    unsigned short u; __builtin_memcpy(&u, &h, 2); return u;
}
__device__ __forceinline__ unsigned int pk2(float a, float b) {
    return (unsigned int)f2bf(a) | ((unsigned int)f2bf(b) << 16);
}
__device__ __forceinline__ float lo16(unsigned int u) { return bf2f((unsigned short)(u & 0xffffu)); }
__device__ __forceinline__ float hi16(unsigned int u) { return bf2f((unsigned short)(u >> 16)); }

#define LOG2E 1.44269504f
#define LN2C  0.69314718f
__device__ __forceinline__ float silu_fast(float x) {
    float e = __builtin_amdgcn_exp2f(-LOG2E * x);
    return x * __builtin_amdgcn_rcpf(1.f + e);
}
__device__ __forceinline__ float softplus_fast(float x) {
    float e = __builtin_amdgcn_exp2f(-LOG2E * fabsf(x));
    return fmaxf(x, 0.f) + LN2C * __builtin_amdgcn_logf(1.f + e);
}

extern "C" __global__ void prep_w(const float* __restrict__ w_in,
                                  const float* __restrict__ ssm_in_w,
                                  const float* __restrict__ x_proj_w,
                                  const float* __restrict__ ssm_out_w,
                                  const float* __restrict__ w_out,
                                  const float* __restrict__ dt_w,
                                  const float* __restrict__ dt_b,
                                  const float* __restrict__ Ds,
                                  unsigned short* __restrict__ wb)
{
    int i = blockIdx.x * 256 + threadIdx.x;
    if (i < OFF_DTW) {
        float v;
        if      (i < OFF_XPROJ ) v = (i < OFF_SSMIN) ? w_in[i] : ssm_in_w[i - OFF_SSMIN];
        else if (i < OFF_SSMOUT) v = x_proj_w[i - OFF_XPROJ];
        else if (i < OFF_WOUT  ) v = ssm_out_w[i - OFF_SSMOUT];
        else                     v = w_out[i - OFF_WOUT];
        wb[i] = f2bf(v);
    } else if (i < WTOT2) {
        int j  = i - OFF_DTW;
        int r  = j & 31;
        int kc = j >> 5;
        float v = (r < DTR) ? dt_w[kc * DTR + r]
                            : (r == 31 ? dt_b[kc] : 0.f);
        wb[i] = f2bf(v);
    } else if (i < WTOT2 + CC) {
        int c = i - WTOT2;
        float* dsum = (float*)(wb + WTOT2);
        dsum[c] = Ds[c] + Ds[CC + c] + Ds[2*CC + c] + Ds[3*CC + c];
    }
}

extern "C" __global__ void __launch_bounds__(NTH)
mamba_fused(const float* __restrict__ x,
            const float* __restrict__ norm_w,  const float* __restrict__ norm_b,
            const float* __restrict__ out_norm_w, const float* __restrict__ out_norm_b,
            const unsigned short* __restrict__ wsb,
            float* __restrict__ out)
{
    __shared__ __align__(16) unsigned short sX [16][SP];   // 6400 B
    __shared__ __align__(16) unsigned short sXD[16][SD];   // 3584 B
    __shared__ float sred [16][8];                          // 512 B (LN1 parts / LN2 wv)
    __shared__ float sred2[16][8];                          // 512 B
    __shared__ __align__(16) float sbc[NK][16];             // 256 B   => ~11.3 KB

    const int tid  = threadIdx.x;
    const int lane = tid & 63;
    const int wv   = tid >> 6;          // 0..1
    const int frow = lane & 15;         // pixel row in D-layout / A-row
    const int kb   = lane >> 4;         // 0..3
    const int pxb  = kb * 4;            // D rows pxb..pxb+3

    const int t   = blockIdx.x;         // 4096 blocks
    const int b   = t >> 10;
    const int rem = t & 1023;
    const int h   = rem >> 3;
    const int w0  = (rem & 7) * 16;

    const float* dsum = (const float*)(wsb + WTOT2);

    // persistent packed-bf16 state (parity-matched tiles): 12 + 12 VGPRs
    unsigned int x2p[6][2];   // silu(x2): producer G1 j=6..11 (nt=12+wv+2(j-6)) -> consumer G4 j'=j-6
    unsigned int zp [6][2];   // silu(z) : producer G2 j=6..11 -> consumer LN2 j'=j-6 (ct=wv+2j')

    // ---------------- LN1 (px/part layout: 8 parts x 24 ch) ---------------------
    {
        const int px = tid & 15, part = tid >> 4;     // part 0..7
        const int c0 = part * 24;
        const size_t base = (((size_t)b * CC + c0) * HH + h) * WW + w0 + px;
        float sum = 0.f, sq = 0.f;
#pragma unroll
        for (int gg = 0; gg < 3; ++gg) {
            float v0 = x[base + (size_t)(gg*8+0) * (HH*WW)];
            float v1 = x[base + (size_t)(gg*8+1) * (HH*WW)];
            float v2 = x[base + (size_t)(gg*8+2) * (HH*WW)];
            float v3 = x[base + (size_t)(gg*8+3) * (HH*WW)];
            float v4 = x[base + (size_t)(gg*8+4) * (HH*WW)];
            float v5 = x[base + (size_t)(gg*8+5) * (HH*WW)];
            float v6 = x[base + (size_t)(gg*8+6) * (HH*WW)];
            float v7 = x[base + (size_t)(gg*8+7) * (HH*WW)];
            sum += v0+v1+v2+v3+v4+v5+v6+v7;
            sq  += v0*v0+v1*v1+v2*v2+v3*v3+v4*v4+v5*v5+v6*v6+v7*v7;
            uint4 pkd;
            pkd.x = pk2(v0, v1); pkd.y = pk2(v2, v3);
            pkd.z = pk2(v4, v5); pkd.w = pk2(v6, v7);
            *(uint4*)(&sX[px][c0 + gg*8]) = pkd;
        }
        sred[px][part] = sum; sred2[px][part] = sq;
        __syncthreads();                                        // BAR 1
        float s = 0.f, q = 0.f;
#pragma unroll
        for (int j = 0; j < 8; ++j) { s += sred[px][j]; q += sred2[px][j]; }
        float mu = s * (1.f / CC);
        float rs = rsqrtf(q * (1.f / CC) - mu * mu + 1e-5f);
#pragma unroll
        for (int gg = 0; gg < 3; ++gg) {
            int c = c0 + gg*8;
            uint4 pkd = *(const uint4*)(&sX[px][c]);
            uint4 o;
            o.x = pk2((lo16(pkd.x)-mu)*rs*norm_w[c+0]+norm_b[c+0],
                      (hi16(pkd.x)-mu)*rs*norm_w[c+1]+norm_b[c+1]);
            o.y = pk2((lo16(pkd.y)-mu)*rs*norm_w[c+2]+norm_b[c+2],
                      (hi16(pkd.y)-mu)*rs*norm_w[c+3]+norm_b[c+3]);
            o.z = pk2((lo16(pkd.z)-mu)*rs*norm_w[c+4]+norm_b[c+4],
                      (hi16(pkd.z)-mu)*rs*norm_w[c+5]+norm_b[c+5]);
            o.w = pk2((lo16(pkd.w)-mu)*rs*norm_w[c+6]+norm_b[c+6],
                      (hi16(pkd.w)-mu)*rs*norm_w[c+7]+norm_b[c+7]);
            *(uint4*)(&sX[px][c]) = o;
        }
        __syncthreads();                                        // BAR 2
    }

    bh8 a[6];
    auto load_a = [&]() {
#pragma unroll
        for (int ks = 0; ks < 6; ++ks)
            a[ks] = *(const bh8*)(&sX[frow][ks * 32 + kb * 8]);
    };
    auto gemm1t = [&](const unsigned short* wB, int nt) -> f4 {
        const unsigned short* wp = wB + (size_t)(nt * 16 + frow) * CC + kb * 8;
        f4 acc = {0.f, 0.f, 0.f, 0.f};
#pragma unroll
        for (int ks = 0; ks < 6; ++ks) {
            bh8 bf = *(const bh8*)(wp + ks * 32);
            acc = MFMA(a[ks], bf, acc);
        }
        return acc;
    };

    // ---------------- GEMM1: p = xn @ w_in^T -> sX = x1, x2p = silu(x2) ---------
    {
        load_a();
        __syncthreads();                                        // BAR 3
        const unsigned short* wB = wsb + OFF_WIN;
#pragma unroll
        for (int j = 0; j < 12; ++j) {
            int nt = wv + 2 * j;
            f4 acc = gemm1t(wB, nt);
            if (j < 6) {
                int o = nt * 16 + frow;
#pragma unroll
                for (int r = 0; r < 4; ++r) sX[pxb + r][o] = f2bf(acc[r]);
            } else {
                x2p[j - 6][0] = pk2(silu_fast(acc[0]), silu_fast(acc[1]));
                x2p[j - 6][1] = pk2(silu_fast(acc[2]), silu_fast(acc[3]));
            }
        }
        __syncthreads();                                        // BAR 4
    }

    // ---------------- GEMM2: u = x1 @ ssm_in^T -> sX = silu(xss), zp = silu(z) --
    {
        load_a();
        __syncthreads();                                        // BAR 5
        const unsigned short* wB = wsb + OFF_SSMIN;
#pragma unroll
        for (int j = 0; j < 12; ++j) {
            int nt = wv + 2 * j;
            f4 acc = gemm1t(wB, nt);
            if (j < 6) {
                int o = nt * 16 + frow;
#pragma unroll
                for (int r = 0; r < 4; ++r) sX[pxb + r][o] = f2bf(silu_fast(acc[r]));
            } else {
                zp[j - 6][0] = pk2(silu_fast(acc[0]), silu_fast(acc[1]));
                zp[j - 6][1] = pk2(silu_fast(acc[2]), silu_fast(acc[3]));
            }
        }
        __syncthreads();                                        // BAR 6
    }

    // ---------------- GEMM3: xd = xss @ x_proj^T (7 tiles) -> sXD ---------------
    {
        load_a();     // xss; writes go to sXD, so no pre-barrier needed
        const unsigned short* wB = wsb + OFF_XPROJ;
#pragma unroll
        for (int j = 0; j < 4; ++j) {
            int nt = wv + 2 * j;
            if (nt < 7) {
                f4 acc = gemm1t(wB, nt);
                int o = nt * 16 + frow;
#pragma unroll
                for (int r = 0; r < 4; ++r) sXD[pxb + r][o] = f2bf(acc[r]);
            }
        }
        __syncthreads();                                        // BAR 7
    }

    // ---------------- bc[k][px] = dot(Bv, Cv) -----------------------------------
    if (tid < 64) {
        int px = tid & 15, k = tid >> 4;
        float acc = 0.f;
#pragma unroll
        for (int s = 0; s < DST; ++s)
            acc += bf2f(sXD[px][k*28 + DTR + s]) * bf2f(sXD[px][k*28 + DTR + DST + s]);
        sbc[k][px] = acc;
    }
    __syncthreads();                                            // BAR 8

    // ---------------- dt-MFMA: y = xss*(sum_k bc*softplus(.) + Dsum) ------------
    // own-parity ct tiles only; y in-place into sX; stats on the fly.
    f4 l2sum = {0.f,0.f,0.f,0.f}, l2sq = {0.f,0.f,0.f,0.f};
    {
        bh8 adt[NK];
#pragma unroll
        for (int k = 0; k < NK; ++k) {
            const unsigned short* rp = &sXD[frow][k * 28];
            bh8 vv;
            if (kb == 0) {
                ushort4 lo = *(const ushort4*)(rp);
                ushort4 hi = *(const ushort4*)(rp + 4);
                vv = bh8{(short)lo.x,(short)lo.y,(short)lo.z,(short)lo.w,
                         (short)hi.x,(short)hi.y,(short)hi.z,(short)hi.w};
            } else if (kb == 1) {
                ushort4 lo = *(const ushort4*)(rp + 8);
                vv = bh8{(short)lo.x,(short)lo.y,(short)lo.z,(short)lo.w,0,0,0,0};
            } else if (kb == 2) {
                vv = bh8{0,0,0,0,0,0,0,0};
            } else {
                vv = bh8{0,0,0,0,0,0,0,(short)0x3F80};   // bf16 1.0 -> col 31 (dt_b)
            }
            adt[k] = vv;
        }
        const unsigned short* wDT = wsb + OFF_DTW;
#pragma unroll
        for (int j = 0; j < 6; ++j) {
            int ct = wv + 2 * j;
            int c  = ct * 16 + frow;
            f4 g = {0.f,0.f,0.f,0.f};
#pragma unroll
            for (int k = 0; k < NK; ++k) {
                bh8 bf = *(const bh8*)(wDT + (((size_t)(k * CC + c)) << 5) + kb * 8);
                f4 d = {0.f,0.f,0.f,0.f};
                d = MFMA(adt[k], bf, d);
                f4 bck = *(const f4*)(&sbc[k][pxb]);
#pragma unroll
                for (int r = 0; r < 4; ++r)
                    g[r] += bck[r] * softplus_fast(d[r]);
            }
            float ds = dsum[c];
#pragma unroll
            for (int r = 0; r < 4; ++r) {
                float yv = bf2f(sX[pxb + r][c]) * (g[r] + ds);
                sX[pxb + r][c] = f2bf(yv);
                l2sum[r] += yv; l2sq[r] += yv * yv;
            }
        }
        // reduce partial stats across the 16-lane frow group
#pragma unroll
        for (int m = 1; m < 16; m <<= 1) {
#pragma unroll
            for (int r = 0; r < 4; ++r) {
                l2sum[r] += __shfl_xor(l2sum[r], m);
                l2sq[r]  += __shfl_xor(l2sq[r],  m);
            }
        }
        if (frow == 0) {
#pragma unroll
            for (int r = 0; r < 4; ++r) {
                sred [pxb + r][wv] = l2sum[r];
                sred2[pxb + r][wv] = l2sq[r];
            }
        }
    }
    __syncthreads();                                            // BAR 9

    // ---------------- LN2 (D-layout), * z(regs) -> sX = yz ----------------------
    {
        f4 mu, rs;
#pragma unroll
        for (int r = 0; r < 4; ++r) {
            float s = sred [pxb + r][0] + sred [pxb + r][1];
            float q = sred2[pxb + r][0] + sred2[pxb + r][1];
            mu[r] = s * (1.f / CC);
            rs[r] = rsqrtf(q * (1.f / CC) - mu[r] * mu[r] + 1e-5f);
        }
#pragma unroll
        for (int j = 0; j < 6; ++j) {
            int ct = wv + 2 * j;
            int c  = ct * 16 + frow;
            float wn = out_norm_w[c], bn = out_norm_b[c];
            float z0 = lo16(zp[j][0]), z1 = hi16(zp[j][0]);
            float z2 = lo16(zp[j][1]), z3 = hi16(zp[j][1]);
            float y0 = bf2f(sX[pxb + 0][c]);
            float y1 = bf2f(sX[pxb + 1][c]);
            float y2 = bf2f(sX[pxb + 2][c]);
            float y3 = bf2f(sX[pxb + 3][c]);
            sX[pxb + 0][c] = f2bf(((y0 - mu[0]) * rs[0] * wn + bn) * z0);
            sX[pxb + 1][c] = f2bf(((y1 - mu[1]) * rs[1] * wn + bn) * z1);
            sX[pxb + 2][c] = f2bf(((y2 - mu[2]) * rs[2] * wn + bn) * z2);
            sX[pxb + 3][c] = f2bf(((y3 - mu[3]) * rs[3] * wn + bn) * z3);
        }
    }
    __syncthreads();                                            // BAR 10

    // ---------------- GEMM4: s = yz @ ssm_out^T; sX = s * silu(x2) --------------
    {
        load_a();
        __syncthreads();                                        // BAR 11
        const unsigned short* wB = wsb + OFF_SSMOUT;
#pragma unroll
        for (int j = 0; j < 6; ++j) {
            int nt = wv + 2 * j;
            f4 acc = gemm1t(wB, nt);
            int o = nt * 16 + frow;
            sX[pxb + 0][o] = f2bf(acc[0] * lo16(x2p[j][0]));
            sX[pxb + 1][o] = f2bf(acc[1] * hi16(x2p[j][0]));
            sX[pxb + 2][o] = f2bf(acc[2] * lo16(x2p[j][1]));
            sX[pxb + 3][o] = f2bf(acc[3] * hi16(x2p[j][1]));
        }
        __syncthreads();                                        // BAR 12
    }

    // ---------------- GEMM5: o = (s*x2) @ w_out^T; out = x + o ------------------
    {
        load_a();
        const unsigned short* wB = wsb + OFF_WOUT;
#pragma unroll
        for (int j = 0; j < 6; ++j) {
            int nt = wv + 2 * j;
            f4 acc = gemm1t(wB, nt);
            int o = nt * 16 + frow;
            const size_t g0 = (((size_t)b * CC + o) * HH + h) * WW + w0 + pxb;
            float4 xv = *(const float4*)(x + g0);
            float4 ov;
            ov.x = xv.x + acc[0];
            ov.y = xv.y + acc[1];
            ov.z = xv.z + acc[2];
            ov.w = xv.w + acc[3];
            *(float4*)(out + g0) = ov;
        }
    }
}

extern "C" void kernel_launch(void* const* d_in, const int* in_sizes, int n_in,
                              void* d_out, int out_size, void* d_ws, size_t ws_size,
                              hipStream_t stream) {
    const float* x          = (const float*)d_in[0];
    const float* norm_w     = (const float*)d_in[1];
    const float* norm_b     = (const float*)d_in[2];
    const float* w_in       = (const float*)d_in[3];
    const float* ssm_in_w   = (const float*)d_in[4];
    const float* x_proj_w   = (const float*)d_in[5];
    const float* dt_w       = (const float*)d_in[6];
    const float* dt_b       = (const float*)d_in[7];
    // d_in[8] = A_logs : unused by the reference computation
    const float* Ds         = (const float*)d_in[9];
    const float* out_norm_w = (const float*)d_in[10];
    const float* out_norm_b = (const float*)d_in[11];
    const float* ssm_out_w  = (const float*)d_in[12];
    const float* w_out      = (const float*)d_in[13];

    unsigned short* wb = (unsigned short*)d_ws;
    int prep_n = WTOT2 + CC;
    prep_w<<<dim3((prep_n + 255) / 256), dim3(256), 0, stream>>>(
        w_in, ssm_in_w, x_proj_w, ssm_out_w, w_out, dt_w, dt_b, Ds, wb);

    mamba_fused<<<dim3(4096), dim3(NTH), 0, stream>>>(
        x, norm_w, norm_b, out_norm_w, out_norm_b, wb, (float*)d_out);
}

// Round 12
// 171.558 us; speedup vs baseline: 2.2087x; 2.2087x over previous
//
#include <hip/hip_runtime.h>
#include <hip/hip_bf16.h>
#include <math.h>

// ChannelMambaBlock fused — Round 12: R4 skeleton + LDS diet -> 6 blocks/CU
// B=4, C=192, H=128, W=128, K=4, DSTATE=8, DTRANK=12
// Block = 256 threads (4 waves), 32 consecutive-W pixels, grid 2048. Proven R4
// structure (pair-ILP GEMMs, x2-in-regs parity trick) with LDS 40.9->22.8KB:
// one recycled activation buffer sX[32][200], z ALSO in regs (same parity trick),
// xd in dedicated sXD[32][112], LN2 in D-layout (within-wave shfl stats).
// launch_bounds(256,3) -> 84-VGPR budget (R1-R3 proven) for x2p+zp state.

#define CC    192
#define HH    128
#define WW    128
#define NK    4
#define DST   8
#define DTR   12
#define TP    32
#define NTH   256
#define SP    200         // sX row stride (400B rows, 16B-aligned)
#define SD    112         // sXD row stride (224B rows)

typedef __attribute__((ext_vector_type(8))) short bh8;   // 8 bf16 = 4 VGPR
typedef __attribute__((ext_vector_type(4))) float f4;

// bf16 weight segments inside d_ws (ushort elems)
#define OFF_WIN    0
#define OFF_SSMIN  73728        // 384*192
#define OFF_XPROJ  147456
#define OFF_SSMOUT 168960       // + 112*192
#define OFF_WOUT   205824
#define OFF_DTW    242688       // + 192*192  -> B_dt [k][c][32]
#define WTOT2      267264       // + 4*192*32
// f32 Dsum[192] at ushort offset WTOT2

#define MFMA(va, vb, vc) __builtin_amdgcn_mfma_f32_16x16x32_bf16(va, vb, vc, 0, 0, 0)

__device__ __forceinline__ float bf2f(unsigned short u) {
    union { unsigned int i; float f; } v; v.i = ((unsigned int)u) << 16; return v.f;
}
__device__ __forceinline__ unsigned short f2bf(float f) {
    __hip_bfloat16 h = __float2bfloat16(f);
    unsigned short u; __builtin_memcpy(&u, &h, 2); return u;
}
__device__ __forceinline__ unsigned int pk2(float a, float b) {
    return (unsigned int)f2bf(a) | ((unsigned int)f2bf(b) << 16);
}
__device__ __forceinline__ float lo16(unsigned int u) { return bf2f((unsigned short)(u & 0xffffu)); }
__device__ __forceinline__ float hi16(unsigned int u) { return bf2f((unsigned short)(u >> 16)); }

#define LOG2E 1.44269504f
#define LN2C  0.69314718f
__device__ __forceinline__ float silu_fast(float x) {
    float e = __builtin_amdgcn_exp2f(-LOG2E * x);
    return x * __builtin_amdgcn_rcpf(1.f + e);
}
__device__ __forceinline__ float softplus_fast(float x) {
    float e = __builtin_amdgcn_exp2f(-LOG2E * fabsf(x));
    return fmaxf(x, 0.f) + LN2C * __builtin_amdgcn_logf(1.f + e);
}

extern "C" __global__ void prep_w(const float* __restrict__ w_in,
                                  const float* __restrict__ ssm_in_w,
                                  const float* __restrict__ x_proj_w,
                                  const float* __restrict__ ssm_out_w,
                                  const float* __restrict__ w_out,
                                  const float* __restrict__ dt_w,
                                  const float* __restrict__ dt_b,
                                  const float* __restrict__ Ds,
                                  unsigned short* __restrict__ wb)
{
    int i = blockIdx.x * NTH + threadIdx.x;
    if (i < OFF_DTW) {
        float v;
        if      (i < OFF_XPROJ ) v = (i < OFF_SSMIN) ? w_in[i] : ssm_in_w[i - OFF_SSMIN];
        else if (i < OFF_SSMOUT) v = x_proj_w[i - OFF_XPROJ];
        else if (i < OFF_WOUT  ) v = ssm_out_w[i - OFF_SSMOUT];
        else                     v = w_out[i - OFF_WOUT];
        wb[i] = f2bf(v);
    } else if (i < WTOT2) {
        int j  = i - OFF_DTW;
        int r  = j & 31;
        int kc = j >> 5;
        float v = (r < DTR) ? dt_w[kc * DTR + r]
                            : (r == 31 ? dt_b[kc] : 0.f);
        wb[i] = f2bf(v);
    } else if (i < WTOT2 + CC) {
        int c = i - WTOT2;
        float* dsum = (float*)(wb + WTOT2);
        dsum[c] = Ds[c] + Ds[CC + c] + Ds[2*CC + c] + Ds[3*CC + c];
    }
}

extern "C" __global__ void __launch_bounds__(NTH, 3)
mamba_fused(const float* __restrict__ x,
            const float* __restrict__ norm_w,  const float* __restrict__ norm_b,
            const float* __restrict__ out_norm_w, const float* __restrict__ out_norm_b,
            const unsigned short* __restrict__ wsb,
            float* __restrict__ out)
{
    __shared__ __align__(16) unsigned short sX [TP][SP];   // 12800 B (recycled)
    __shared__ __align__(16) unsigned short sXD[TP][SD];   //  7168 B
    __shared__ float sred [TP][8];                          //  1024 B (LN1)
    __shared__ float sred2[TP][8];                          //  1024 B
    __shared__ float smu[TP];                               //   128 B
    __shared__ float srs[TP];                               //   128 B
    __shared__ __align__(16) float sbcT[NK][TP];            //   512 B  => 22784 B

    const int tid  = threadIdx.x;
    const int lane = tid & 63;
    const int wave = tid >> 6;
    const int frow = lane & 15;
    const int kb   = lane >> 4;
    const int pxb  = kb * 4;

    const int t   = blockIdx.x;          // 2048 blocks
    const int b   = t >> 9;
    const int rem = t & 511;
    const int h   = rem >> 2;
    const int w0g = (rem & 3) * TP;

    const float* dsum = (const float*)(wsb + WTOT2);

    // persistent packed-bf16 state (parity trick, R4-proven for x2):
    // producer tile nt = wave+12+4j  <->  consumer tile/ct = wave+4j, j=0..2
    unsigned int x2p0[3][2], x2p1[3][2];   // silu(x2): m=0 rows pxb+r / m=1 rows 16+pxb+r
    unsigned int zp0 [3][2], zp1 [3][2];   // silu(z)

    // ---------------- Phase 0: load x + LayerNorm1 -> sX = xn (bf16) ------------
    {
        const int px = tid & 31, part = tid >> 5;
        float sum = 0.f, sq = 0.f;
        const size_t base = (((size_t)b * CC) * HH + h) * WW + w0g + px;
        for (int i = 0; i < 24; ++i) {
            int c = part * 24 + i;
            float v = x[base + (size_t)c * (HH * WW)];
            sum += v; sq += v * v;
            sX[px][c] = f2bf(v);
        }
        sred[px][part] = sum; sred2[px][part] = sq;
        __syncthreads();                                   // BAR 1
        if (part == 0) {
            float s = 0.f, q = 0.f;
            for (int j = 0; j < 8; ++j) { s += sred[px][j]; q += sred2[px][j]; }
            float mu  = s * (1.f / CC);
            float var = q * (1.f / CC) - mu * mu;
            smu[px] = mu; srs[px] = rsqrtf(var + 1e-5f);
        }
        __syncthreads();                                   // BAR 2
        const float mu = smu[px], rs = srs[px];
        for (int i = 0; i < 24; ++i) {
            int c = part * 24 + i;
            float v = bf2f(sX[px][c]);
            v = (v - mu) * rs * norm_w[c] + norm_b[c];
            sX[px][c] = f2bf(v);
        }
        __syncthreads();                                   // BAR 3
    }

    bh8 a[2][6];
    auto load_a = [&]() {
#pragma unroll
        for (int m = 0; m < 2; ++m)
#pragma unroll
            for (int ks = 0; ks < 6; ++ks)
                a[m][ks] = *(const bh8*)(&sX[m * 16 + frow][ks * 32 + kb * 8]);
    };
    auto gemm_pair = [&](const unsigned short* wB, int n0, int n1,
                         f4& p0, f4& p1, f4& q0, f4& q1) {
        const unsigned short* wp0 = wB + (size_t)(n0 + frow) * CC + kb * 8;
        const unsigned short* wp1 = wB + (size_t)(n1 + frow) * CC + kb * 8;
#pragma unroll
        for (int ks = 0; ks < 6; ++ks) {
            bh8 b0 = *(const bh8*)(wp0 + ks * 32);
            bh8 b1 = *(const bh8*)(wp1 + ks * 32);
            p0 = MFMA(a[0][ks], b0, p0);
            p1 = MFMA(a[1][ks], b0, p1);
            q0 = MFMA(a[0][ks], b1, q0);
            q1 = MFMA(a[1][ks], b1, q1);
        }
    };
    auto gemm_one = [&](const unsigned short* wB, int n0, f4& p0, f4& p1) {
        const unsigned short* wp = wB + (size_t)(n0 + frow) * CC + kb * 8;
#pragma unroll
        for (int ks = 0; ks < 6; ++ks) {
            bh8 bf = *(const bh8*)(wp + ks * 32);
            p0 = MFMA(a[0][ks], bf, p0);
            p1 = MFMA(a[1][ks], bf, p1);
        }
    };
    auto st_sX = [&](int o, const f4& c0, const f4& c1) {
#pragma unroll
        for (int r = 0; r < 4; ++r) {
            sX[pxb + r][o]      = f2bf(c0[r]);
            sX[16 + pxb + r][o] = f2bf(c1[r]);
        }
    };
    auto st_sX_silu = [&](int o, const f4& c0, const f4& c1) {
#pragma unroll
        for (int r = 0; r < 4; ++r) {
            sX[pxb + r][o]      = f2bf(silu_fast(c0[r]));
            sX[16 + pxb + r][o] = f2bf(silu_fast(c1[r]));
        }
    };

    // ---------------- GEMM1: p = xn @ w_in^T -> sX = x1, regs = silu(x2) --------
    {
        load_a();
        __syncthreads();                                   // BAR 4
        const unsigned short* wB = wsb + OFF_WIN;
        {   // tiles (w, w+4): both x1
            f4 p0={0,0,0,0},p1={0,0,0,0},q0={0,0,0,0},q1={0,0,0,0};
            gemm_pair(wB, wave * 16, (wave + 4) * 16, p0, p1, q0, q1);
            st_sX(wave * 16 + frow, p0, p1);
            st_sX((wave + 4) * 16 + frow, q0, q1);
        }
        {   // tiles (w+8, w+12): x1, x2 slot 0
            f4 p0={0,0,0,0},p1={0,0,0,0},q0={0,0,0,0},q1={0,0,0,0};
            gemm_pair(wB, (wave + 8) * 16, (wave + 12) * 16, p0, p1, q0, q1);
            st_sX((wave + 8) * 16 + frow, p0, p1);
            x2p0[0][0] = pk2(silu_fast(q0[0]), silu_fast(q0[1]));
            x2p0[0][1] = pk2(silu_fast(q0[2]), silu_fast(q0[3]));
            x2p1[0][0] = pk2(silu_fast(q1[0]), silu_fast(q1[1]));
            x2p1[0][1] = pk2(silu_fast(q1[2]), silu_fast(q1[3]));
        }
        {   // tiles (w+16, w+20): x2 slots 1,2
            f4 p0={0,0,0,0},p1={0,0,0,0},q0={0,0,0,0},q1={0,0,0,0};
            gemm_pair(wB, (wave + 16) * 16, (wave + 20) * 16, p0, p1, q0, q1);
            x2p0[1][0] = pk2(silu_fast(p0[0]), silu_fast(p0[1]));
            x2p0[1][1] = pk2(silu_fast(p0[2]), silu_fast(p0[3]));
            x2p1[1][0] = pk2(silu_fast(p1[0]), silu_fast(p1[1]));
            x2p1[1][1] = pk2(silu_fast(p1[2]), silu_fast(p1[3]));
            x2p0[2][0] = pk2(silu_fast(q0[0]), silu_fast(q0[1]));
            x2p0[2][1] = pk2(silu_fast(q0[2]), silu_fast(q0[3]));
            x2p1[2][0] = pk2(silu_fast(q1[0]), silu_fast(q1[1]));
            x2p1[2][1] = pk2(silu_fast(q1[2]), silu_fast(q1[3]));
        }
        __syncthreads();                                   // BAR 5
    }

    // ---------------- GEMM2: u = x1 @ ssm_in^T -> sX = silu(xss), regs = z ------
    {
        load_a();
        __syncthreads();                                   // BAR 6
        const unsigned short* wB = wsb + OFF_SSMIN;
        {   // tiles (w, w+4): both xss
            f4 p0={0,0,0,0},p1={0,0,0,0},q0={0,0,0,0},q1={0,0,0,0};
            gemm_pair(wB, wave * 16, (wave + 4) * 16, p0, p1, q0, q1);
            st_sX_silu(wave * 16 + frow, p0, p1);
            st_sX_silu((wave + 4) * 16 + frow, q0, q1);
        }
        {   // tiles (w+8, w+12): xss, z slot 0
            f4 p0={0,0,0,0},p1={0,0,0,0},q0={0,0,0,0},q1={0,0,0,0};
            gemm_pair(wB, (wave + 8) * 16, (wave + 12) * 16, p0, p1, q0, q1);
            st_sX_silu((wave + 8) * 16 + frow, p0, p1);
            zp0[0][0] = pk2(silu_fast(q0[0]), silu_fast(q0[1]));
            zp0[0][1] = pk2(silu_fast(q0[2]), silu_fast(q0[3]));
            zp1[0][0] = pk2(silu_fast(q1[0]), silu_fast(q1[1]));
            zp1[0][1] = pk2(silu_fast(q1[2]), silu_fast(q1[3]));
        }
        {   // tiles (w+16, w+20): z slots 1,2
            f4 p0={0,0,0,0},p1={0,0,0,0},q0={0,0,0,0},q1={0,0,0,0};
            gemm_pair(wB, (wave + 16) * 16, (wave + 20) * 16, p0, p1, q0, q1);
            zp0[1][0] = pk2(silu_fast(p0[0]), silu_fast(p0[1]));
            zp0[1][1] = pk2(silu_fast(p0[2]), silu_fast(p0[3]));
            zp1[1][0] = pk2(silu_fast(p1[0]), silu_fast(p1[1]));
            zp1[1][1] = pk2(silu_fast(p1[2]), silu_fast(p1[3]));
            zp0[2][0] = pk2(silu_fast(q0[0]), silu_fast(q0[1]));
            zp0[2][1] = pk2(silu_fast(q0[2]), silu_fast(q0[3]));
            zp1[2][0] = pk2(silu_fast(q1[0]), silu_fast(q1[1]));
            zp1[2][1] = pk2(silu_fast(q1[2]), silu_fast(q1[3]));
        }
        __syncthreads();                                   // BAR 7
    }

    // ---------------- GEMM3: xd = xss @ x_proj^T (7 tiles) -> sXD ---------------
    {
        load_a();      // reads sX (stable); writes go to sXD only
        const unsigned short* wB = wsb + OFF_XPROJ;
        f4 p0={0,0,0,0},p1={0,0,0,0},q0={0,0,0,0},q1={0,0,0,0};
        gemm_pair(wB, wave * 16, (wave + 4) * 16, p0, p1, q0, q1);
        {
            int o = wave * 16 + frow;
#pragma unroll
            for (int r = 0; r < 4; ++r) {
                sXD[pxb + r][o]      = f2bf(p0[r]);
                sXD[16 + pxb + r][o] = f2bf(p1[r]);
            }
        }
        if (wave < 3) {      // tile 7 (wave 3) is dead; SD=112 has no room for it
            int o = (wave + 4) * 16 + frow;
#pragma unroll
            for (int r = 0; r < 4; ++r) {
                sXD[pxb + r][o]      = f2bf(q0[r]);
                sXD[16 + pxb + r][o] = f2bf(q1[r]);
            }
        }
        __syncthreads();                                   // BAR 8
    }

    // ---------------- bc[k][px] = dot(Bv, Cv) -----------------------------------
    if (tid < TP * NK) {
        int px = tid & 31, k = tid >> 5;
        float acc = 0.f;
        for (int s = 0; s < DST; ++s)
            acc += bf2f(sXD[px][k*28 + DTR + s]) * bf2f(sXD[px][k*28 + DTR + DST + s]);
        sbcT[k][px] = acc;
    }
    __syncthreads();                                       // BAR 9

    // ---------------- dt-MFMA: y = xss*(sum_k bc*softplus(.) + Dsum) -> sX ------
    {
        bh8 adt[NK][2];
#pragma unroll
        for (int k = 0; k < NK; ++k)
#pragma unroll
            for (int m = 0; m < 2; ++m) {
                const unsigned short* rp = &sXD[m * 16 + frow][k * 28];
                bh8 vv;
                if (kb == 0) {
                    ushort4 lo = *(const ushort4*)(rp);
                    ushort4 hi = *(const ushort4*)(rp + 4);
                    vv = bh8{(short)lo.x,(short)lo.y,(short)lo.z,(short)lo.w,
                             (short)hi.x,(short)hi.y,(short)hi.z,(short)hi.w};
                } else if (kb == 1) {
                    ushort4 lo = *(const ushort4*)(rp + 8);
                    vv = bh8{(short)lo.x,(short)lo.y,(short)lo.z,(short)lo.w,0,0,0,0};
                } else if (kb == 2) {
                    vv = bh8{0,0,0,0,0,0,0,0};
                } else {
                    vv = bh8{0,0,0,0,0,0,0,(short)0x3F80};   // bf16 1.0 -> col 31
                }
                adt[k][m] = vv;
            }
        const unsigned short* wDT = wsb + OFF_DTW;
#pragma unroll
        for (int j = 0; j < 3; ++j) {
            int ct = wave + 4 * j;
            int c  = ct * 16 + frow;
            f4 g0 = {0.f,0.f,0.f,0.f}, g1 = {0.f,0.f,0.f,0.f};
#pragma unroll
            for (int k = 0; k < NK; ++k) {
                bh8 bf = *(const bh8*)(wDT + (((size_t)(k * CC + c)) << 5) + kb * 8);
                f4 d0 = {0.f,0.f,0.f,0.f}, d1 = {0.f,0.f,0.f,0.f};
                d0 = MFMA(adt[k][0], bf, d0);
                d1 = MFMA(adt[k][1], bf, d1);
                f4 bc0 = *(const f4*)(&sbcT[k][pxb]);
                f4 bc1 = *(const f4*)(&sbcT[k][16 + pxb]);
#pragma unroll
                for (int r = 0; r < 4; ++r) {
                    g0[r] += bc0[r] * softplus_fast(d0[r]);
                    g1[r] += bc1[r] * softplus_fast(d1[r]);
                }
            }
            float ds = dsum[c];
#pragma unroll
            for (int r = 0; r < 4; ++r) {
                float y0 = bf2f(sX[pxb + r][c]) * (g0[r] + ds);
                sX[pxb + r][c] = f2bf(y0);
                float y1 = bf2f(sX[16 + pxb + r][c]) * (g1[r] + ds);
                sX[16 + pxb + r][c] = f2bf(y1);
            }
        }
    }
    __syncthreads();                                       // BAR 10

    // ---------------- LN2 stats (D-layout, within-wave) -------------------------
    f4 mu0, rs0, mu1, rs1;
    {
        f4 s0 = {0,0,0,0}, q0v = {0,0,0,0}, s1 = {0,0,0,0}, q1v = {0,0,0,0};
#pragma unroll
        for (int ct2 = 0; ct2 < 12; ++ct2) {
            int c = ct2 * 16 + frow;
#pragma unroll
            for (int r = 0; r < 4; ++r) {
                float ya = bf2f(sX[pxb + r][c]);
                float yb = bf2f(sX[16 + pxb + r][c]);
                s0[r] += ya; q0v[r] += ya * ya;
                s1[r] += yb; q1v[r] += yb * yb;
            }
        }
#pragma unroll
        for (int m = 1; m < 16; m <<= 1) {
#pragma unroll
            for (int r = 0; r < 4; ++r) {
                s0[r]  += __shfl_xor(s0[r],  m);
                q0v[r] += __shfl_xor(q0v[r], m);
                s1[r]  += __shfl_xor(s1[r],  m);
                q1v[r] += __shfl_xor(q1v[r], m);
            }
        }
#pragma unroll
        for (int r = 0; r < 4; ++r) {
            mu0[r] = s0[r] * (1.f / CC);
            rs0[r] = rsqrtf(q0v[r] * (1.f / CC) - mu0[r] * mu0[r] + 1e-5f);
            mu1[r] = s1[r] * (1.f / CC);
            rs1[r] = rsqrtf(q1v[r] * (1.f / CC) - mu1[r] * mu1[r] + 1e-5f);
        }
    }
    __syncthreads();                                       // BAR 11 (stats read done)

    // ---------------- LN2 normalize own ct tiles, * z(regs) -> sX = yz ----------
    {
#pragma unroll
        for (int j = 0; j < 3; ++j) {
            int ct = wave + 4 * j;
            int c  = ct * 16 + frow;
            float wn = out_norm_w[c], bn = out_norm_b[c];
#pragma unroll
            for (int r = 0; r < 4; ++r) {
                float za = (r < 2) ? ((r & 1) ? hi16(zp0[j][0]) : lo16(zp0[j][0]))
                                   : ((r & 1) ? hi16(zp0[j][1]) : lo16(zp0[j][1]));
                float zb = (r < 2) ? ((r & 1) ? hi16(zp1[j][0]) : lo16(zp1[j][0]))
                                   : ((r & 1) ? hi16(zp1[j][1]) : lo16(zp1[j][1]));
                float ya = bf2f(sX[pxb + r][c]);
                float yb = bf2f(sX[16 + pxb + r][c]);
                sX[pxb + r][c]      = f2bf(((ya - mu0[r]) * rs0[r] * wn + bn) * za);
                sX[16 + pxb + r][c] = f2bf(((yb - mu1[r]) * rs1[r] * wn + bn) * zb);
            }
        }
    }
    __syncthreads();                                       // BAR 12

    // ---------------- GEMM4: s = yz @ ssm_out^T; sX = s * silu(x2) --------------
    {
        load_a();
        __syncthreads();                                   // BAR 13
        const unsigned short* wB = wsb + OFF_SSMOUT;
        {   // pair: tiles w (x2 slot 0), w+4 (x2 slot 1)
            f4 p0={0,0,0,0},p1={0,0,0,0},q0={0,0,0,0},q1={0,0,0,0};
            gemm_pair(wB, wave * 16, (wave + 4) * 16, p0, p1, q0, q1);
            int o0 = wave * 16 + frow, o1 = (wave + 4) * 16 + frow;
            sX[pxb + 0][o0]      = f2bf(p0[0] * lo16(x2p0[0][0]));
            sX[pxb + 1][o0]      = f2bf(p0[1] * hi16(x2p0[0][0]));
            sX[pxb + 2][o0]      = f2bf(p0[2] * lo16(x2p0[0][1]));
            sX[pxb + 3][o0]      = f2bf(p0[3] * hi16(x2p0[0][1]));
            sX[16 + pxb + 0][o0] = f2bf(p1[0] * lo16(x2p1[0][0]));
            sX[16 + pxb + 1][o0] = f2bf(p1[1] * hi16(x2p1[0][0]));
            sX[16 + pxb + 2][o0] = f2bf(p1[2] * lo16(x2p1[0][1]));
            sX[16 + pxb + 3][o0] = f2bf(p1[3] * hi16(x2p1[0][1]));
            sX[pxb + 0][o1]      = f2bf(q0[0] * lo16(x2p0[1][0]));
            sX[pxb + 1][o1]      = f2bf(q0[1] * hi16(x2p0[1][0]));
            sX[pxb + 2][o1]      = f2bf(q0[2] * lo16(x2p0[1][1]));
            sX[pxb + 3][o1]      = f2bf(q0[3] * hi16(x2p0[1][1]));
            sX[16 + pxb + 0][o1] = f2bf(q1[0] * lo16(x2p1[1][0]));
            sX[16 + pxb + 1][o1] = f2bf(q1[1] * hi16(x2p1[1][0]));
            sX[16 + pxb + 2][o1] = f2bf(q1[2] * lo16(x2p1[1][1]));
            sX[16 + pxb + 3][o1] = f2bf(q1[3] * hi16(x2p1[1][1]));
        }
        {   // single: tile w+8 (x2 slot 2)
            f4 p0={0,0,0,0},p1={0,0,0,0};
            gemm_one(wB, (wave + 8) * 16, p0, p1);
            int o = (wave + 8) * 16 + frow;
            sX[pxb + 0][o]      = f2bf(p0[0] * lo16(x2p0[2][0]));
            sX[pxb + 1][o]      = f2bf(p0[1] * hi16(x2p0[2][0]));
            sX[pxb + 2][o]      = f2bf(p0[2] * lo16(x2p0[2][1]));
            sX[pxb + 3][o]      = f2bf(p0[3] * hi16(x2p0[2][1]));
            sX[16 + pxb + 0][o] = f2bf(p1[0] * lo16(x2p1[2][0]));
            sX[16 + pxb + 1][o] = f2bf(p1[1] * hi16(x2p1[2][0]));
            sX[16 + pxb + 2][o] = f2bf(p1[2] * lo16(x2p1[2][1]));
            sX[16 + pxb + 3][o] = f2bf(p1[3] * hi16(x2p1[2][1]));
        }
        __syncthreads();                                   // BAR 14
    }

    // ---------------- GEMM5: o = (s*x2) @ w_out^T; out = x + o ------------------
    {
        load_a();
        const unsigned short* wB = wsb + OFF_WOUT;
        auto st_out = [&](int o, const f4& c0, const f4& c1) {
            const size_t g0 = (((size_t)b * CC + o) * HH + h) * WW + w0g;
#pragma unroll
            for (int r = 0; r < 4; ++r) {
                out[g0 + pxb + r]      = x[g0 + pxb + r]      + c0[r];
                out[g0 + 16 + pxb + r] = x[g0 + 16 + pxb + r] + c1[r];
            }
        };
        {   // pair: tiles w, w+4
            f4 p0={0,0,0,0},p1={0,0,0,0},q0={0,0,0,0},q1={0,0,0,0};
            gemm_pair(wB, wave * 16, (wave + 4) * 16, p0, p1, q0, q1);
            st_out(wave * 16 + frow, p0, p1);
            st_out((wave + 4) * 16 + frow, q0, q1);
        }
        {   // single: tile w+8
            f4 p0={0,0,0,0},p1={0,0,0,0};
            gemm_one(wB, (wave + 8) * 16, p0, p1);
            st_out((wave + 8) * 16 + frow, p0, p1);
        }
    }
}

extern "C" void kernel_launch(void* const* d_in, const int* in_sizes, int n_in,
                              void* d_out, int out_size, void* d_ws, size_t ws_size,
                              hipStream_t stream) {
    const float* x          = (const float*)d_in[0];
    const float* norm_w     = (const float*)d_in[1];
    const float* norm_b     = (const float*)d_in[2];
    const float* w_in       = (const float*)d_in[3];
    const float* ssm_in_w   = (const float*)d_in[4];
    const float* x_proj_w   = (const float*)d_in[5];
    const float* dt_w       = (const float*)d_in[6];
    const float* dt_b       = (const float*)d_in[7];
    // d_in[8] = A_logs : unused by the reference computation
    const float* Ds         = (const float*)d_in[9];
    const float* out_norm_w = (const float*)d_in[10];
    const float* out_norm_b = (const float*)d_in[11];
    const float* ssm_out_w  = (const float*)d_in[12];
    const float* w_out      = (const float*)d_in[13];

    unsigned short* wb = (unsigned short*)d_ws;
    int prep_n = WTOT2 + CC;
    prep_w<<<dim3((prep_n + NTH - 1) / NTH), dim3(NTH), 0, stream>>>(
        w_in, ssm_in_w, x_proj_w, ssm_out_w, w_out, dt_w, dt_b, Ds, wb);

    mamba_fused<<<dim3(2048), dim3(NTH), 0, stream>>>(
        x, norm_w, norm_b, out_norm_w, out_norm_b, wb, (float*)d_out);
}